// Round 6
// baseline (80.221 us; speedup 1.0000x reference)
//
#include <hip/hip_runtime.h>

// Spatial transformer, bilinear sampling, NCHW fp32.
// X: (B, C, H, W) = (32, 3, 512, 512), theta: (B, 6), out: (B, C, H, W).
//
// R6: LDS-staged 32x32 output tiles. Each block computes the exact source
//     bounding box of its tile from the 4 corner pixels (same fma sequence
//     as the per-px math -> provably encloses all px; +-1 pad), stages the
//     clamped bbox rows into LDS with coalesced loads, then gathers from
//     LDS (ds_read2_b32 pairs, DS pipe) instead of divergent vmem gathers.
//     Border replication is encoded in the staged data (clamp at load), so
//     the per-px path needs no selects. Rare oversized bbox (outlier theta)
//     -> block-uniform fallback to the R4 per-px dwordx2 gather path.
//     Keeps: nt stores, XCD-contiguous swizzle.

#define ST_H 512
#define ST_W 512
#define ST_C 3
#define ST_HW (ST_H * ST_W)
#define TILE 32
#define RMAX 48      // staged rows
#define CPITCH 49    // staged cols == LDS pitch (odd -> bank-friendly)

typedef float f2 __attribute__((ext_vector_type(2)));
typedef float f4 __attribute__((ext_vector_type(4)));
struct __attribute__((packed, aligned(4))) f2_a4 { f2 v; };

__global__ __launch_bounds__(256) void st_bilinear_tiled(
    const float* __restrict__ X,
    const float* __restrict__ theta,
    float* __restrict__ out,
    int chunk)
{
    __shared__ float sb[ST_C][RMAX][CPITCH];   // 28224 B

    // XCD swizzle: each XCD owns a contiguous range of blocks (grid % 8 == 0)
    int bid = blockIdx.x;
    bid = (bid & 7) * chunk + (bid >> 3);

    const int b    = bid >> 8;          // 256 tiles per image (16x16)
    const int tile = bid & 255;
    const int h0 = (tile >> 4) << 5;
    const int w0 = (tile & 15) << 5;

    const float* t = theta + b * 6;
    const float t00 = t[0], t01 = t[1], t02 = t[2];
    const float t10 = t[3], t11 = t[4], t12 = t[5];
    const float STEP = (float)(2.0 / 511.0);

    // ---- exact bbox from the 4 corner pixels (identical fma sequence) ----
    float xminf = 1e30f, xmaxf = -1e30f, yminf = 1e30f, ymaxf = -1e30f;
    {
        const float xs0 = fmaf((float)w0, STEP, -1.0f);
        const float xs1 = fmaf((float)(w0 + TILE - 1), STEP, -1.0f);
        const float ys0 = fmaf((float)h0, STEP, -1.0f);
        const float ys1 = fmaf((float)(h0 + TILE - 1), STEP, -1.0f);
        const float xsv[2] = { xs0, xs1 };
        const float ysv[2] = { ys0, ys1 };
#pragma unroll
        for (int i = 0; i < 2; ++i)
#pragma unroll
            for (int j = 0; j < 2; ++j) {
                const float cxc = fmaf(t01, ysv[j], t02);
                const float cyc = fmaf(t11, ysv[j], t12);
                const float xx = (fmaf(t00, xsv[i], cxc) + 1.0f) * 256.0f;
                const float yy = (fmaf(t10, xsv[i], cyc) + 1.0f) * 256.0f;
                xminf = fminf(xminf, xx); xmaxf = fmaxf(xmaxf, xx);
                yminf = fminf(yminf, yy); ymaxf = fmaxf(ymaxf, yy);
            }
    }
    const int xlo = (int)floorf(xminf) - 1;
    const int ylo = (int)floorf(yminf) - 1;
    const int RX  = (int)floorf(xmaxf) + 2 - xlo + 1;
    const int RY  = (int)floorf(ymaxf) + 2 - ylo + 1;

    const int tid  = threadIdx.x;
    const int trow = tid >> 3;          // 4 consecutive px per thread
    const int tcol = (tid & 7) << 2;
    const int h = h0 + trow;

    const float yg = fmaf((float)h, STEP, -1.0f);
    const float cx = fmaf(t01, yg, t02);
    const float cy = fmaf(t11, yg, t12);

    const float* __restrict__ Xb = X + (size_t)b * (ST_C * ST_HW);
    float* __restrict__ ob = out + (size_t)b * (ST_C * ST_HW) + h * ST_W + (w0 + tcol);

    float acc[ST_C][4];

    if (RX <= CPITCH && RY <= RMAX) {
        // ---------------- staged path ----------------
        const int lane = tid & 63, wid = tid >> 6;
        const int colc = min(max(xlo + lane, 0), ST_W - 1);   // clamp -> border replicate
#pragma unroll
        for (int c = 0; c < ST_C; ++c) {
            const float* __restrict__ Xc = Xb + c * ST_HW;
            for (int r = wid; r < RY; r += 4) {
                const int rowc = min(max(ylo + r, 0), ST_H - 1);
                if (lane < CPITCH)
                    sb[c][r][lane] = Xc[rowc * ST_W + colc];
            }
        }
        __syncthreads();

#pragma unroll
        for (int j = 0; j < 4; ++j) {
            const float xg = fmaf((float)(w0 + tcol + j), STEP, -1.0f);
            const float x = (fmaf(t00, xg, cx) + 1.0f) * 256.0f;
            const float y = (fmaf(t10, xg, cy) + 1.0f) * 256.0f;
            const int x0 = (int)floorf(x);
            const int y0 = (int)floorf(y);
            // weights use CLIPPED coords cast to float (reference semantics)
            const int x0c = min(max(x0, 0), ST_W - 1);
            const int x1c = min(max(x0 + 1, 0), ST_W - 1);
            const int y0c = min(max(y0, 0), ST_H - 1);
            const int y1c = min(max(y0 + 1, 0), ST_H - 1);
            const float wa = ((float)x1c - x) * ((float)y1c - y);
            const float wb = ((float)x1c - x) * (y - (float)y0c);
            const float wc = (x - (float)x0c) * ((float)y1c - y);
            const float wd = (x - (float)x0c) * (y - (float)y0c);
            const int lx = x0 - xlo;    // in [1, RX-3]; staged data already clamped
            const int ly = y0 - ylo;    // in [1, RY-3]
#pragma unroll
            for (int c = 0; c < ST_C; ++c) {
                const f2 p = ((const f2_a4*)&sb[c][ly][lx])->v;       // (Ia, Ic)
                const f2 q = ((const f2_a4*)&sb[c][ly + 1][lx])->v;   // (Ib, Id)
                acc[c][j] = wa * p.x + wb * q.x + wc * p.y + wd * q.y;
            }
        }
    } else {
        // ---------------- fallback: R4 per-px dwordx2 gathers ----------------
#pragma unroll
        for (int j = 0; j < 4; ++j) {
            const float xg = fmaf((float)(w0 + tcol + j), STEP, -1.0f);
            const float x = (fmaf(t00, xg, cx) + 1.0f) * 256.0f;
            const float y = (fmaf(t10, xg, cy) + 1.0f) * 256.0f;
            const int x0 = (int)floorf(x);
            const int y0 = (int)floorf(y);
            const int x0c = min(max(x0, 0), ST_W - 1);
            const int x1c = min(max(x0 + 1, 0), ST_W - 1);
            const int y0c = min(max(y0, 0), ST_H - 1);
            const int y1c = min(max(y0 + 1, 0), ST_H - 1);
            const float wa = ((float)x1c - x) * ((float)y1c - y);
            const float wb = ((float)x1c - x) * (y - (float)y0c);
            const float wc = (x - (float)x0c) * ((float)y1c - y);
            const float wd = (x - (float)x0c) * (y - (float)y0c);

            const int xa = min(max(x0, 0), ST_W - 2);
            const bool hi = (x0 >= ST_W - 1);
            const bool lo = (x0 < 0);
            const int ia = y0c * ST_W + xa;
            const int ib = y1c * ST_W + xa;
#pragma unroll
            for (int c = 0; c < ST_C; ++c) {
                const float* __restrict__ Xc = Xb + c * ST_HW;
                const f2 p = ((const f2_a4*)(Xc + ia))->v;
                const f2 q = ((const f2_a4*)(Xc + ib))->v;
                const float Ia = hi ? p.y : p.x;
                const float Ic = lo ? p.x : p.y;
                const float Ib = hi ? q.y : q.x;
                const float Id = lo ? q.x : q.y;
                acc[c][j] = wa * Ia + wb * Ib + wc * Ic + wd * Id;
            }
        }
    }

    // ---- stores: dwordx4 nontemporal (output has zero reuse) ----
#pragma unroll
    for (int c = 0; c < ST_C; ++c) {
        f4 v;
        v.x = acc[c][0]; v.y = acc[c][1]; v.z = acc[c][2]; v.w = acc[c][3];
        __builtin_nontemporal_store(v, (f4*)(ob + c * ST_HW));
    }
}

extern "C" void kernel_launch(void* const* d_in, const int* in_sizes, int n_in,
                              void* d_out, int out_size, void* d_ws, size_t ws_size,
                              hipStream_t stream) {
    const float* X     = (const float*)d_in[0];
    const float* theta = (const float*)d_in[1];
    float* out         = (float*)d_out;

    const int B = in_sizes[1] / 6;          // 32
    const int block = 256;                  // 32x32 px tile per block
    const int grid = B * 256;               // 8192 blocks, divisible by 8
    const int chunk = grid / 8;             // blocks per XCD

    st_bilinear_tiled<<<grid, block, 0, stream>>>(X, theta, out, chunk);
}

// Round 7
// 39.400 us; speedup vs baseline: 2.0360x; 2.0360x over previous
//
#include <hip/hip_runtime.h>

// Spatial transformer, bilinear sampling, NCHW fp32.
// X: (B, C, H, W) = (32, 3, 512, 512), theta: (B, 6), out: (B, C, H, W).
//
// R7: R4's per-px paired gathers (dwordx2 covers x0/x1 corners) kept intact;
//     only the block->pixel mapping changes: each block = 64x4 output tile
//     (wave = one 64-px row segment; 4 waves = 4 adjacent rows). The q-row
//     of output row h is the p-row of row h+1, so gather lines are reused
//     through L1 (5 KB working set/block) instead of re-fetched from L2.
//     Keeps: 4B lane stride in gathers, nt stores, XCD-contiguous swizzle.

#define ST_H 512
#define ST_W 512
#define ST_C 3
#define ST_HW (ST_H * ST_W)

typedef float f2 __attribute__((ext_vector_type(2)));
struct __attribute__((packed, aligned(4))) f2_a4 { f2 v; };

__global__ __launch_bounds__(256) void st_bilinear_kernel(
    const float* __restrict__ X,
    const float* __restrict__ theta,
    float* __restrict__ out,
    int chunk)
{
    // XCD swizzle: each XCD owns a contiguous range of blocks (grid % 8 == 0).
    int bid = blockIdx.x;
    bid = (bid & 7) * chunk + (bid >> 3);

    const int b   = bid >> 10;            // 1024 tiles per image
    const int idx = bid & 1023;
    const int tx  = idx & 7;              // 8 tiles of 64 px across
    const int ty  = idx >> 3;             // 128 tiles of 4 rows down

    const int tid = (int)threadIdx.x;
    const int h = (ty << 2) + (tid >> 6); // wave id = row within tile
    const int w = (tx << 6) + (tid & 63); // lane  = column within tile

    const float* t = theta + b * 6;
    const float t00 = t[0], t01 = t[1], t02 = t[2];
    const float t10 = t[3], t11 = t[4], t12 = t[5];

    const float STEP = (float)(2.0 / 511.0);
    const float xg = fmaf((float)w, STEP, -1.0f);
    const float yg = fmaf((float)h, STEP, -1.0f);

    const float x = (fmaf(t00, xg, fmaf(t01, yg, t02)) + 1.0f) * 256.0f;
    const float y = (fmaf(t10, xg, fmaf(t11, yg, t12)) + 1.0f) * 256.0f;

    const int x0 = (int)floorf(x);
    const int y0 = (int)floorf(y);

    const int x0c = min(max(x0, 0), ST_W - 1);
    const int x1c = min(max(x0 + 1, 0), ST_W - 1);
    const int y0c = min(max(y0, 0), ST_H - 1);
    const int y1c = min(max(y0 + 1, 0), ST_H - 1);

    // weights use CLIPPED coords cast to float (reference semantics)
    const float x0f = (float)x0c, x1f = (float)x1c;
    const float y0f = (float)y0c, y1f = (float)y1c;
    const float wa = (x1f - x) * (y1f - y);
    const float wb = (x1f - x) * (y - y0f);
    const float wc = (x - x0f) * (y1f - y);
    const float wd = (x - x0f) * (y - y0f);

    // pair-gather start column; covers {x0c, x1c} for all clamp cases
    const int xa = min(max(x0, 0), ST_W - 2);
    const bool hi = (x0 >= ST_W - 1);   // both corners clamped to W-1 -> .y
    const bool lo = (x0 < 0);           // both corners clamped to 0   -> .x

    const int ia = y0c * ST_W + xa;     // row y0, elements xa, xa+1
    const int ib = y1c * ST_W + xa;     // row y1

    const float* __restrict__ Xb = X + (size_t)b * (ST_C * ST_HW);
    float* __restrict__ ob = out + (size_t)b * (ST_C * ST_HW) + h * ST_W + w;

#pragma unroll
    for (int c = 0; c < ST_C; ++c) {
        const float* __restrict__ Xc = Xb + c * ST_HW;
        const f2 p = ((const f2_a4*)(Xc + ia))->v;   // (Ia, Ic) pre-select
        const f2 q = ((const f2_a4*)(Xc + ib))->v;   // (Ib, Id) pre-select
        const float Ia = hi ? p.y : p.x;
        const float Ic = lo ? p.x : p.y;
        const float Ib = hi ? q.y : q.x;
        const float Id = lo ? q.x : q.y;
        const float v = wa * Ia + wb * Ib + wc * Ic + wd * Id;
        // nontemporal: output has zero reuse; keep L1/L2 for the gathers
        __builtin_nontemporal_store(v, ob + c * ST_HW);
    }
}

extern "C" void kernel_launch(void* const* d_in, const int* in_sizes, int n_in,
                              void* d_out, int out_size, void* d_ws, size_t ws_size,
                              hipStream_t stream) {
    const float* X     = (const float*)d_in[0];
    const float* theta = (const float*)d_in[1];
    float* out         = (float*)d_out;

    const int B = in_sizes[1] / 6;          // 32
    const int block = 256;                  // 64x4 px tile per block
    const int grid = B * 1024;              // 32768 blocks, divisible by 8
    const int chunk = grid / 8;             // blocks per XCD

    st_bilinear_kernel<<<grid, block, 0, stream>>>(X, theta, out, chunk);
}